// Round 4
// baseline (5871.145 us; speedup 1.0000x reference)
//
#include <hip/hip_runtime.h>
#include <stdint.h>
#include <math.h>

// CipherRNN: B=64, S=1024, V=128, E=512, H=512, L=2, O=256
#define B_ 64
#define S_ 1024
#define V_ 128
#define E_ 512
#define H_ 512
#define O_ 256

#define D0_ 16          // h0 ring depth (slots)
#define DX_ 16          // x1 ring depth
#define D1_ 4           // h1 ring depth
#define SLOT2 (B_ * H_ * 2)   // u32s per ring slot (8B pairs: {data, tag})

typedef __attribute__((ext_vector_type(8))) short bf16x8;
typedef __attribute__((ext_vector_type(4))) float f32x4;
typedef __attribute__((ext_vector_type(4))) unsigned int u32x4;
typedef __attribute__((ext_vector_type(2))) unsigned int u32x2;
typedef unsigned short u16;
typedef unsigned int u32;

__device__ __forceinline__ u16 f2bf(float f) {
  unsigned u = __builtin_bit_cast(unsigned, f);
  u = u + 0x7FFFu + ((u >> 16) & 1u);   // RNE
  return (u16)(u >> 16);
}
__device__ __forceinline__ float bf2f(u16 h) {
  unsigned u = ((unsigned)h) << 16;
  return __builtin_bit_cast(float, u);
}

// fast tanh: 1 - 2/(exp2(2*log2e*x)+1); exact at +-inf, ~1e-7 rel err
__device__ __forceinline__ float fast_tanh(float x) {
  float a = __builtin_amdgcn_exp2f(x * 2.8853900817779268f);
  return 1.0f - 2.0f * __builtin_amdgcn_rcpf(a + 1.0f);
}

// ---- L3-coherent (bypass L1+L2) communication ops ----
__device__ __forceinline__ u32x4 ld_sc1_x4(const u32* p) {
  u32x4 v;
  asm volatile("global_load_dwordx4 %0, %1, off sc0 sc1" : "=v"(v) : "v"(p));
  return v;
}
__device__ __forceinline__ u32x2 ld_sc1_x2(const u32* p) {
  u32x2 v;
  asm volatile("global_load_dwordx2 %0, %1, off sc0 sc1" : "=v"(v) : "v"(p));
  return v;
}
__device__ __forceinline__ void st_sc1_x2(u32* p, u32 d, u32 tag) {
  u32x2 v = {d, tag};
  asm volatile("global_store_dwordx2 %0, %1, off sc0 sc1" :: "v"(p), "v"(v) : "memory");
}
__device__ __forceinline__ void st_sc1_u32(u32* p, u32 v) {
  asm volatile("global_store_dword %0, %1, off sc0 sc1" :: "v"(p), "v"(v) : "memory");
}
__device__ __forceinline__ void vm0_fence() {
  asm volatile("s_waitcnt vmcnt(0)" ::: "memory");
  __builtin_amdgcn_sched_barrier(0);
}

__device__ __forceinline__ u32 pk_hi(u32 a, u32 b) { return (a & 0xffffu) | (b << 16); }
__device__ __forceinline__ u32 pk_lo(u32 a, u32 b) { return (a >> 16) | (b & 0xffff0000u); }

// ---------------------------------------------------------------------------
// EW0[v][n] = sum_e emb[v][e]*Wxh0[n][e] + bh0[n]   (f32 exact, V=128)
// ---------------------------------------------------------------------------
__global__ void k_embed(const float* __restrict__ emb, const float* __restrict__ Wxh0,
                        const float* __restrict__ bh0, float* __restrict__ EW0) {
  __shared__ float es[E_];
  const int v = blockIdx.x;
  for (int e = threadIdx.x; e < E_; e += blockDim.x) es[e] = emb[v * E_ + e];
  __syncthreads();
  for (int h = threadIdx.x; h < H_; h += blockDim.x) {
    const float* wr = Wxh0 + (size_t)h * E_;
    float acc = bh0[h];
    #pragma unroll 4
    for (int e = 0; e < E_; e += 4)
      acc += es[e] * wr[e] + es[e+1] * wr[e+1] + es[e+2] * wr[e+2] + es[e+3] * wr[e+3];
    EW0[(size_t)v * H_ + h] = acc;
  }
}

// ---------------------------------------------------------------------------
// Persistent 3-stage pipeline with tag-in-data rings (no flags, no store-ack
// on the critical path). 48 blocks = 3 roles x 4 groups x 4 col-blocks.
// Ring element = 8B pair {packed u32 (bf16 hi|lo or f32), tag = t+1}.
// ---------------------------------------------------------------------------
__global__ __launch_bounds__(512, 2) void k_pipe(
    const float* __restrict__ Whh,   // [2][512][512]
    const float* __restrict__ Wxh,   // [2][512][512]
    const int* __restrict__ ids,     // [B][S]
    const float* __restrict__ EW0,   // [V][H] f32
    const float* __restrict__ bh,    // [2][512]
    u32* __restrict__ h0r,           // [D0][64*512] pairs
    u32* __restrict__ x1r,           // [DX][64*512] pairs
    u32* __restrict__ h1r,           // [D1][64*512] pairs
    u16* __restrict__ h1full,        // [B*S][512] bf16 (plain cached)
    u32* __restrict__ x1prog,        // [16] consumer progress (x1 stage)
    u32* __restrict__ r1prog)        // [16] consumer progress (rnn1 stage)
{
  __shared__ u32 lds_hi[16 * 256];   // 16 KB: A-tile hi (16 rows x 512 bf16)
  __shared__ u32 lds_lo[16 * 256];   // 16 KB: A-tile lo

  const int tid  = threadIdx.x;
  const int wave = tid >> 6, lane = tid & 63;
  const int l15 = lane & 15, lhi = lane >> 4;
  const int bid = blockIdx.x;
  const int role = bid >> 4, sub = bid & 15;
  const int g = sub >> 2, cb = sub & 3;
  const int n = cb * 128 + wave * 16 + l15;   // this lane's output column

  // ---- resident weights (hi/lo bf16 B-fragments), plain cached loads ----
  const float* Wsel = (role == 0) ? Whh
                    : (role == 1) ? (Wxh + (size_t)H_ * H_)
                                  : (Whh + (size_t)H_ * H_);
  bf16x8 whi[16], wlo[16];
  {
    const float* wr = Wsel + (size_t)n * H_ + lhi * 8;
    #pragma unroll
    for (int ks = 0; ks < 16; ++ks) {
      const float* src = wr + ks * 32;
      bf16x8 h, l;
      #pragma unroll
      for (int j = 0; j < 8; ++j) {
        const float v = src[j];
        const u16 hb = f2bf(v);
        h[j] = (short)hb;
        l[j] = (short)f2bf(v - bf2f(hb));
      }
      whi[ks] = h; wlo[ks] = l;
    }
  }

  // precomputed swizzled LDS byte offsets; A-frag row=l15, k-granule ks*4+lhi
  int aoff[16];
  {
    const int sw = l15 & 7;
    #pragma unroll
    for (int ks = 0; ks < 16; ++ks)
      aoff[ks] = l15 * 1024 + (((ks * 4 + lhi) ^ sw) << 4);
  }

  // ---- stage a 16x512 tile of tagged pairs into LDS, polling tags ----
  auto stage = [&](const u32* slot, u32 want) {
    const int r = tid >> 5;          // row within group tile
    const int m = tid & 31;          // 16-col chunk
    const u32* p = slot + ((size_t)(g * 16 + r) * 512 + m * 16) * 2;
    u32x4 q[8];
    for (;;) {
      #pragma unroll
      for (int i = 0; i < 8; ++i) q[i] = ld_sc1_x4(p + i * 4);
      vm0_fence();
      u32 bad = 0;
      #pragma unroll
      for (int i = 0; i < 8; ++i) bad |= (q[i].y ^ want) | (q[i].w ^ want);
      if (!bad) break;
    }
    u32 d[16];
    #pragma unroll
    for (int i = 0; i < 8; ++i) { d[2*i] = q[i].x; d[2*i+1] = q[i].z; }
    const int sw = r & 7;
    const int ga = (m * 2) ^ sw, gb = (m * 2 + 1) ^ sw;
    u32x4 hia = { pk_hi(d[0],d[1]),  pk_hi(d[2],d[3]),  pk_hi(d[4],d[5]),  pk_hi(d[6],d[7]) };
    u32x4 hib = { pk_hi(d[8],d[9]),  pk_hi(d[10],d[11]),pk_hi(d[12],d[13]),pk_hi(d[14],d[15]) };
    u32x4 loa = { pk_lo(d[0],d[1]),  pk_lo(d[2],d[3]),  pk_lo(d[4],d[5]),  pk_lo(d[6],d[7]) };
    u32x4 lob = { pk_lo(d[8],d[9]),  pk_lo(d[10],d[11]),pk_lo(d[12],d[13]),pk_lo(d[14],d[15]) };
    *(u32x4*)&lds_hi[r * 256 + (ga << 2)] = hia;
    *(u32x4*)&lds_hi[r * 256 + (gb << 2)] = hib;
    *(u32x4*)&lds_lo[r * 256 + (ga << 2)] = loa;
    *(u32x4*)&lds_lo[r * 256 + (gb << 2)] = lob;
  };

  // ---- emulated-fp32 matmul from LDS tile (3 independent MFMA chains) ----
  auto mm3 = [&](f32x4& out) {
    f32x4 c0 = {0.f,0.f,0.f,0.f}, c1 = c0, c2 = c0;
    #pragma unroll
    for (int ks = 0; ks < 16; ++ks) {
      bf16x8 ah = *(const bf16x8*)((const char*)lds_hi + aoff[ks]);
      bf16x8 al = *(const bf16x8*)((const char*)lds_lo + aoff[ks]);
      c0 = __builtin_amdgcn_mfma_f32_16x16x32_bf16(ah, whi[ks], c0, 0, 0, 0);
      c1 = __builtin_amdgcn_mfma_f32_16x16x32_bf16(al, whi[ks], c1, 0, 0, 0);
      c2 = __builtin_amdgcn_mfma_f32_16x16x32_bf16(ah, wlo[ks], c2, 0, 0, 0);
    }
    out = c0 + c1 + c2;
  };

  // lazy backpressure gate: wait until min(prog[0..3]) >= need
  auto gate = [&](const u32* prog, u32 need) {
    if (tid == 0) {
      for (;;) {
        u32x4 v = ld_sc1_x4(prog);
        vm0_fence();
        if (v.x >= need && v.y >= need && v.z >= need && v.w >= need) break;
        __builtin_amdgcn_s_sleep(8);
      }
    }
    __syncthreads();
  };

  if (role == 0) {                    // ======== layer-0 recurrence ========
    for (int t = 0; t < S_; ++t) {
      float ew[4];
      #pragma unroll
      for (int j = 0; j < 4; ++j) {
        const int b = g * 16 + lhi * 4 + j;
        ew[j] = EW0[(size_t)ids[b * S_ + t] * H_ + n];
      }
      if ((t & 7) == 0 && t >= D0_) gate(x1prog + g * 4, (u32)(t - 8));
      f32x4 acc = {0.f,0.f,0.f,0.f};
      if (t > 0) {
        stage(h0r + (size_t)((t - 1) & (D0_ - 1)) * SLOT2, (u32)t);
        __syncthreads();
        mm3(acc);
      }
      u32* wslot = h0r + (size_t)(t & (D0_ - 1)) * SLOT2;
      #pragma unroll
      for (int j = 0; j < 4; ++j) {
        const int b = g * 16 + lhi * 4 + j;
        const float h = fast_tanh(acc[j] + ew[j]);
        const u16 hb = f2bf(h);
        const u16 lb = f2bf(h - bf2f(hb));
        st_sc1_x2(wslot + ((size_t)b * 512 + n) * 2, (u32)hb | ((u32)lb << 16), (u32)(t + 1));
      }
      __syncthreads();   // LDS WAR: all mm3 reads done before next stage writes
    }
  } else if (role == 1) {             // ======== x1 = h0 @ Wxh1^T + bh1 ========
    const float bias = bh[H_ + n];
    for (int t = 0; t < S_; ++t) {
      if ((t & 7) == 0 && t >= DX_) gate(r1prog + g * 4, (u32)(t - 8));
      stage(h0r + (size_t)(t & (D0_ - 1)) * SLOT2, (u32)(t + 1));
      __syncthreads();
      f32x4 acc;
      mm3(acc);
      u32* xslot = x1r + (size_t)(t & (DX_ - 1)) * SLOT2;
      #pragma unroll
      for (int j = 0; j < 4; ++j) {
        const int b = g * 16 + lhi * 4 + j;
        const float v = acc[j] + bias;
        st_sc1_x2(xslot + ((size_t)b * 512 + n) * 2, __builtin_bit_cast(u32, v), (u32)(t + 1));
      }
      __syncthreads();
      if (tid == 0) st_sc1_u32(x1prog + g * 4 + cb, (u32)(t + 1));
    }
  } else {                            // ======== layer-1 recurrence ========
    for (int t = 0; t < S_; ++t) {
      // poll tagged x1 pairs directly (per-lane 4 pairs)
      const u32* xslot = x1r + (size_t)(t & (DX_ - 1)) * SLOT2;
      u32x2 xv[4];
      {
        const u32 want = (u32)(t + 1);
        for (;;) {
          #pragma unroll
          for (int j = 0; j < 4; ++j) {
            const int b = g * 16 + lhi * 4 + j;
            xv[j] = ld_sc1_x2(xslot + ((size_t)b * 512 + n) * 2);
          }
          vm0_fence();
          u32 bad = 0;
          #pragma unroll
          for (int j = 0; j < 4; ++j) bad |= xv[j].y ^ want;
          if (!bad) break;
        }
      }
      f32x4 acc = {0.f,0.f,0.f,0.f};
      if (t > 0) {
        stage(h1r + (size_t)((t - 1) & (D1_ - 1)) * SLOT2, (u32)t);
        __syncthreads();
        mm3(acc);
      }
      u32* wslot = h1r + (size_t)(t & (D1_ - 1)) * SLOT2;
      #pragma unroll
      for (int j = 0; j < 4; ++j) {
        const int b = g * 16 + lhi * 4 + j;
        const float h = fast_tanh(acc[j] + __builtin_bit_cast(float, xv[j].x));
        const u16 hb = f2bf(h);
        const u16 lb = f2bf(h - bf2f(hb));
        st_sc1_x2(wslot + ((size_t)b * 512 + n) * 2, (u32)hb | ((u32)lb << 16), (u32)(t + 1));
        h1full[((size_t)b * S_ + t) * H_ + n] = hb;   // plain cached store
      }
      __syncthreads();
      if (tid == 0) st_sc1_u32(r1prog + g * 4 + cb, (u32)(t + 1));
    }
  }
}

// ---------------------------------------------------------------------------
// out[m][o] = sum_k h1[m][k]*Why[o][k] + by[o]   (f32 out)
// ---------------------------------------------------------------------------
__global__ void k_gemm_out(const u16* __restrict__ A, const float* __restrict__ Bw,
                           const float* __restrict__ bias, float* __restrict__ outp) {
  const int tid  = threadIdx.x;
  const int wave = tid >> 6, lane = tid & 63;
  const int l15 = lane & 15, lhi = lane >> 4;
  const int m0  = blockIdx.x * 16;
  const int ncb = wave * 64;

  const u16* arow = A + ((size_t)(m0 + l15)) * H_ + lhi * 8;
  bf16x8 afr[16];
  #pragma unroll
  for (int ks = 0; ks < 16; ++ks) afr[ks] = *(const bf16x8*)(arow + ks * 32);

  f32x4 acc[4];
  #pragma unroll
  for (int nt = 0; nt < 4; ++nt) {
    const int nn = ncb + nt * 16 + l15;
    const float* wr = Bw + (size_t)nn * H_ + lhi * 8;
    f32x4 z = {0.f, 0.f, 0.f, 0.f};
    acc[nt] = z;
    #pragma unroll
    for (int ks = 0; ks < 16; ++ks) {
      const float* src = wr + ks * 32;
      bf16x8 w;
      #pragma unroll
      for (int j = 0; j < 8; ++j) w[j] = (short)f2bf(src[j]);
      acc[nt] = __builtin_amdgcn_mfma_f32_16x16x32_bf16(afr[ks], w, acc[nt], 0, 0, 0);
    }
  }
  #pragma unroll
  for (int nt = 0; nt < 4; ++nt) {
    const int nn = ncb + nt * 16 + l15;
    const float bs = bias[nn];
    #pragma unroll
    for (int j = 0; j < 4; ++j)
      outp[(size_t)(m0 + lhi * 4 + j) * O_ + nn] = acc[nt][j] + bs;
  }
}

// ---------------------------------------------------------------------------
extern "C" void kernel_launch(void* const* d_in, const int* in_sizes, int n_in,
                              void* d_out, int out_size, void* d_ws, size_t ws_size,
                              hipStream_t stream) {
  const int*   ids = (const int*)d_in[0];
  const float* emb = (const float*)d_in[1];
  const float* Wxh = (const float*)d_in[2];
  const float* Whh = (const float*)d_in[3];
  const float* bh  = (const float*)d_in[4];
  const float* Why = (const float*)d_in[5];
  const float* by  = (const float*)d_in[6];
  float* out = (float*)d_out;

  char* ws = (char*)d_ws;
  size_t off = 0;
  float* EW0  = (float*)(ws + off); off += (size_t)V_ * H_ * 4;           // 256 KB
  u32* h0r    = (u32*)(ws + off);   off += (size_t)D0_ * SLOT2 * 4;       // 4 MB
  u32* x1r    = (u32*)(ws + off);   off += (size_t)DX_ * SLOT2 * 4;       // 4 MB
  u32* h1r    = (u32*)(ws + off);   off += (size_t)D1_ * SLOT2 * 4;       // 1 MB
  u32* x1prog = (u32*)(ws + off);   off += 64;
  u32* r1prog = (u32*)(ws + off);   off += 64;
  u16* h1full = (u16*)(ws + off);   off += (size_t)B_ * S_ * H_ * 2;      // 67 MB

  // rings + progress words must be zero at the start of every call
  const size_t zlen = (size_t)(D0_ + DX_ + D1_) * SLOT2 * 4 + 128;
  hipMemsetAsync(h0r, 0, zlen, stream);

  k_embed<<<dim3(V_), dim3(256), 0, stream>>>(emb, Wxh, bh, EW0);

  k_pipe<<<dim3(48), dim3(512), 0, stream>>>(Whh, Wxh, ids, EW0, bh,
                                             h0r, x1r, h1r, h1full,
                                             x1prog, r1prog);

  k_gemm_out<<<dim3((B_ * S_) / 16), dim3(256), 0, stream>>>(h1full, Why, by, out);
}

// Round 7
// 3930.607 us; speedup vs baseline: 1.4937x; 1.4937x over previous
//
#include <hip/hip_runtime.h>
#include <stdint.h>

// CipherRNN: B=64, S=1024, V=128, E=512, H=512, L=2, O=256
#define B_ 64
#define S_ 1024
#define V_ 128
#define E_ 512
#define H_ 512
#define O_ 256
#define SLOTU 32768              // u32 per ring slot (64 rows x 512 cols)

typedef __attribute__((ext_vector_type(8))) short bf16x8;
typedef __attribute__((ext_vector_type(4))) float f32x4;
typedef __attribute__((ext_vector_type(4))) unsigned int u32x4;
typedef __attribute__((ext_vector_type(2))) unsigned int u32x2;
typedef unsigned short u16;
typedef unsigned int u32;

__device__ __forceinline__ u16 f2bf(float f) {
  unsigned u = __builtin_bit_cast(unsigned, f);
  u = u + 0x7FFFu + ((u >> 16) & 1u);   // RNE
  return (u16)(u >> 16);
}
__device__ __forceinline__ float bf2f(u16 h) {
  unsigned u = ((unsigned)h) << 16;
  return __builtin_bit_cast(float, u);
}
// fast tanh via exp2: ~1e-7 rel err; numerically proven in round 4 (passed)
__device__ __forceinline__ float fast_tanh(float x) {
  float a = __builtin_amdgcn_exp2f(x * 2.8853900817779268f);
  return 1.0f - 2.0f * __builtin_amdgcn_rcpf(a + 1.0f);
}
__device__ __forceinline__ u32 pk_hi(u32 a, u32 b) { return (a & 0xffffu) | (b << 16); }
__device__ __forceinline__ u32 pk_lo(u32 a, u32 b) { return (a >> 16) | (b & 0xffff0000u); }

// ---- L3-coherent (bypass L1+L2, no cache-maintenance) ops — proven round 3/4
__device__ __forceinline__ u32x4 ld_sc1_x4(const u32* p) {
  u32x4 v;
  asm volatile("global_load_dwordx4 %0, %1, off sc0 sc1" : "=v"(v) : "v"(p));
  return v;
}
__device__ __forceinline__ u32 ld_sc1_u32(const u32* p) {
  u32 v;
  asm volatile("global_load_dword %0, %1, off sc0 sc1" : "=v"(v) : "v"(p));
  return v;
}
__device__ __forceinline__ void st_sc1_u32(u32* p, u32 v) {
  asm volatile("global_store_dword %0, %1, off sc0 sc1" :: "v"(p), "v"(v) : "memory");
}
__device__ __forceinline__ void st_short_nt(u16* p, u32 v) {
  asm volatile("global_store_short %0, %1, off nt" :: "v"(p), "v"(v) : "memory");
}
__device__ __forceinline__ void vm0_fence() {
  asm volatile("s_waitcnt vmcnt(0)" ::: "memory");
  __builtin_amdgcn_sched_barrier(0);
}
__device__ __forceinline__ void poll4(const u32* p, u32 tgt) {
  for (;;) {
    u32x4 v;
    asm volatile("global_load_dwordx4 %0, %1, off sc0 sc1\n\ts_waitcnt vmcnt(0)"
                 : "=v"(v) : "v"(p) : "memory");
    if (v.x >= tgt && v.y >= tgt && v.z >= tgt && v.w >= tgt) return;
    __builtin_amdgcn_s_sleep(1);
  }
}

// ---------------------------------------------------------------------------
// EW0[v][n] = sum_e emb[v][e]*Wxh0[n][e] + bh0[n]   (f32 exact, V=128)
// ---------------------------------------------------------------------------
__global__ void k_embed(const float* __restrict__ emb, const float* __restrict__ Wxh0,
                        const float* __restrict__ bh0, float* __restrict__ EW0) {
  __shared__ float es[E_];
  const int v = blockIdx.x;
  for (int e = threadIdx.x; e < E_; e += blockDim.x) es[e] = emb[v * E_ + e];
  __syncthreads();
  for (int h = threadIdx.x; h < H_; h += blockDim.x) {
    const float* wr = Wxh0 + (size_t)h * E_;
    float acc = bh0[h];
    #pragma unroll 4
    for (int e = 0; e < E_; e += 4)
      acc += es[e] * wr[e] + es[e+1] * wr[e+1] + es[e+2] * wr[e+2] + es[e+3] * wr[e+3];
    EW0[(size_t)v * H_ + h] = acc;
  }
}

// ---------------------------------------------------------------------------
// Persistent 3-stage pipeline (round-3 protocol, sc0+sc1/L3 everywhere).
// 48 blocks = 3 roles x 4 groups (16 batch rows) x 4 col-blocks (128 cols).
// NEW vs round 3: self-column LDS bypass (recurrence blocks stage only the
// 3 sibling slices = 24KB; own slice written to LDS by the epilogue),
// double-buffered u16 hi/lo LDS tiles, fast_tanh, h1full stores unfenced.
// ---------------------------------------------------------------------------
__global__ __launch_bounds__(512, 2) void k_pipe(
    const float* __restrict__ Whh, const float* __restrict__ Wxh,
    const int* __restrict__ ids, const float* __restrict__ EW0,
    const float* __restrict__ bh,
    u32* __restrict__ h0r,        // [16][64][512] packed u32 {hb | lb<<16}
    u32* __restrict__ x1r,        // [16][64][512] f32 bits
    u32* __restrict__ h1r,        // [4][64][512] packed
    u16* __restrict__ h1full,     // [B*S][512] bf16
    u32* __restrict__ fa)         // flag arena (zeroed each call)
{
  // two u16 planes (hi/lo), double-buffered: 2 bufs x 16 rows x 512 cols x 2B
  __shared__ u32 lds_hi_w[2 * 4096];   // 32 KB
  __shared__ u32 lds_lo_w[2 * 4096];   // 32 KB

  const int tid  = threadIdx.x;
  const int wave = tid >> 6, lane = tid & 63;
  const int l15 = lane & 15, lhi = lane >> 4;
  const int bid = blockIdx.x;
  const int role = bid >> 4, sub = bid & 15;
  const int g = sub >> 2, cb = sub & 3;
  const int n = cb * 128 + wave * 16 + l15;   // this lane's output column
  const int goff = g * 16 * 512;              // group offset inside a ring slot

  u32* h0f = fa;                 // [4 groups][16 slots][4 cb]
  u32* x1f = fa + 256;
  u32* h1f = fa + 512;

  // ---- resident weights (hi/lo bf16 B-fragments), plain cached loads ----
  const float* Wsel = (role == 0) ? Whh
                    : (role == 1) ? (Wxh + (size_t)H_ * H_)
                                  : (Whh + (size_t)H_ * H_);
  bf16x8 whi[16], wlo[16];
  {
    const float* wr = Wsel + (size_t)n * H_ + lhi * 8;
    #pragma unroll
    for (int ks = 0; ks < 16; ++ks) {
      const float* src = wr + ks * 32;
      bf16x8 h, l;
      #pragma unroll
      for (int j = 0; j < 8; ++j) {
        const float v = src[j];
        const u16 hb = f2bf(v);
        h[j] = (short)hb;
        l[j] = (short)f2bf(v - bf2f(hb));
      }
      whi[ks] = h; wlo[ks] = l;
    }
  }

  // A-frag swizzled byte offsets: row=l15, k = ks*32 + lhi*8 (+0..7)
  // byte = row*1024 + ((granule ^ (row&7)) << 4) + (k&7)*2, granule = k>>3
  int aoff[16];
  {
    const int sw = l15 & 7;
    #pragma unroll
    for (int ks = 0; ks < 16; ++ks)
      aoff[ks] = l15 * 1024 + (((ks * 4 + lhi) ^ sw) << 4);
  }

  // ---- stage one sibling 16x128 slice into LDS buf (deinterleave hi/lo) ----
  const int sr = tid >> 5, sm = tid & 31;      // 16 rows x 32 col-chunks(4)
  auto stage_wr = [&](int buf, int cs, u32x4 q) {
    const int byte = buf * 16384 + sr * 1024 + (sm & 1) * 8 +
                     ((((cs << 4) + (sm >> 1)) ^ (sr & 7)) << 4);
    u32x2 hi = { pk_hi(q.x, q.y), pk_hi(q.z, q.w) };
    u32x2 lo = { pk_lo(q.x, q.y), pk_lo(q.z, q.w) };
    *(u32x2*)((char*)lds_hi_w + byte) = hi;
    *(u32x2*)((char*)lds_lo_w + byte) = lo;
  };
  // stage the 3 sibling slices (skip own cb: it's already in LDS)
  auto stage3 = [&](const u32* base, int buf) {
    const u32* rowp = base + sr * 512 + sm * 4;
    const int c0 = (cb + 1) & 3, c1 = (cb + 2) & 3, c2 = (cb + 3) & 3;
    u32x4 q0 = ld_sc1_x4(rowp + c0 * 128);
    u32x4 q1 = ld_sc1_x4(rowp + c1 * 128);
    u32x4 q2 = ld_sc1_x4(rowp + c2 * 128);
    vm0_fence();
    stage_wr(buf, c0, q0); stage_wr(buf, c1, q1); stage_wr(buf, c2, q2);
  };
  // stage all 4 slices (role 1)
  auto stage4 = [&](const u32* base, int buf) {
    const u32* rowp = base + sr * 512 + sm * 4;
    u32x4 q0 = ld_sc1_x4(rowp);
    u32x4 q1 = ld_sc1_x4(rowp + 128);
    u32x4 q2 = ld_sc1_x4(rowp + 256);
    u32x4 q3 = ld_sc1_x4(rowp + 384);
    vm0_fence();
    stage_wr(buf, 0, q0); stage_wr(buf, 1, q1); stage_wr(buf, 2, q2); stage_wr(buf, 3, q3);
  };

  // ---- emulated-fp32 matmul from LDS tile (3 independent MFMA chains) ----
  auto mm3 = [&](int buf, f32x4& out) {
    const char* bh_ = (const char*)lds_hi_w + buf * 16384;
    const char* bl_ = (const char*)lds_lo_w + buf * 16384;
    f32x4 c0 = {0.f,0.f,0.f,0.f}, c1 = c0, c2 = c0;
    #pragma unroll
    for (int ks = 0; ks < 16; ++ks) {
      bf16x8 ah = *(const bf16x8*)(bh_ + aoff[ks]);
      bf16x8 al = *(const bf16x8*)(bl_ + aoff[ks]);
      c0 = __builtin_amdgcn_mfma_f32_16x16x32_bf16(ah, whi[ks], c0, 0, 0, 0);
      c1 = __builtin_amdgcn_mfma_f32_16x16x32_bf16(al, whi[ks], c1, 0, 0, 0);
      c2 = __builtin_amdgcn_mfma_f32_16x16x32_bf16(ah, wlo[ks], c2, 0, 0, 0);
    }
    out = c0 + c1 + c2;
  };

  // ---- epilogue self-write: own 4 outputs (col n, rows lhi*4+j) into LDS ----
  auto self_write = [&](int buf, const u16* hbv, const u16* lbv) {
    char* bh_ = (char*)lds_hi_w + buf * 16384;
    char* bl_ = (char*)lds_lo_w + buf * 16384;
    const int gcol = n >> 3, coff = (n & 7) * 2;
    #pragma unroll
    for (int j = 0; j < 4; ++j) {
      const int r = lhi * 4 + j;
      const int byte = r * 1024 + ((gcol ^ (r & 7)) << 4) + coff;
      *(u16*)(bh_ + byte) = hbv[j];
      *(u16*)(bl_ + byte) = lbv[j];
    }
  };

  if (role == 0) {                     // ======== layer-0 recurrence ========
    for (int t = 0; t < S_; ++t) {
      float ew[4];                      // flag-independent prefetch (L2-hot)
      #pragma unroll
      for (int j = 0; j < 4; ++j) {
        const int b = g * 16 + lhi * 4 + j;
        ew[j] = EW0[(size_t)ids[b * S_ + t] * H_ + n];
      }
      if (tid == 0) {
        if (t > 0) poll4(&h0f[((g << 4) | ((t - 1) & 15)) * 4], (u32)t);
        if ((t & 7) == 0 && t >= 16)
          poll4(&x1f[((g << 4) | ((t - 9) & 15)) * 4], (u32)(t - 8));
      }
      __syncthreads();
      const int cur = t & 1;
      f32x4 acc = {0.f,0.f,0.f,0.f};
      if (t > 0) {
        stage3(h0r + (size_t)((t - 1) & 15) * SLOTU + goff, cur);
        __syncthreads();
        mm3(cur, acc);
      }
      u32* wsl = h0r + (size_t)(t & 15) * SLOTU;
      u16 hbv[4], lbv[4];
      #pragma unroll
      for (int j = 0; j < 4; ++j) {
        const int b = g * 16 + lhi * 4 + j;
        const float h = fast_tanh(acc[j] + ew[j]);
        hbv[j] = f2bf(h);
        lbv[j] = f2bf(h - bf2f(hbv[j]));
        st_sc1_u32(wsl + (size_t)b * 512 + n, (u32)hbv[j] | ((u32)lbv[j] << 16));
      }
      self_write(cur ^ 1, hbv, lbv);    // h[t] self cols for step t+1
      vm0_fence();
      __syncthreads();
      if (tid == 0) st_sc1_u32(&h0f[((g << 4) | (t & 15)) * 4 + cb], (u32)(t + 1));
    }
  } else if (role == 1) {              // ======== x1 = h0 @ Wxh1^T + bh1 ========
    const float bias = bh[H_ + n];
    for (int t = 0; t < S_; ++t) {
      if (tid == 0) {
        poll4(&h0f[((g << 4) | (t & 15)) * 4], (u32)(t + 1));
        if ((t & 7) == 0 && t >= 16)
          poll4(&h1f[((g << 4) | ((t - 9) & 15)) * 4], (u32)(t - 8));
      }
      __syncthreads();
      const int cur = t & 1;
      stage4(h0r + (size_t)(t & 15) * SLOTU + goff, cur);
      __syncthreads();
      f32x4 acc;
      mm3(cur, acc);
      u32* xsl = x1r + (size_t)(t & 15) * SLOTU;
      #pragma unroll
      for (int j = 0; j < 4; ++j) {
        const int b = g * 16 + lhi * 4 + j;
        const float v = acc[j] + bias;
        st_sc1_u32(xsl + (size_t)b * 512 + n, __builtin_bit_cast(u32, v));
      }
      vm0_fence();
      __syncthreads();
      if (tid == 0) st_sc1_u32(&x1f[((g << 4) | (t & 15)) * 4 + cb], (u32)(t + 1));
    }
  } else {                             // ======== layer-1 recurrence ========
    for (int t = 0; t < S_; ++t) {
      if (tid == 0) {
        poll4(&x1f[((g << 4) | (t & 15)) * 4], (u32)(t + 1));
        if (t > 0) poll4(&h1f[((g << 4) | ((t - 1) & 15)) * 4], (u32)t);
      }
      __syncthreads();
      // issue x1 loads; stage3's (or explicit) vm0 covers them before use
      const u32* xsl = x1r + (size_t)(t & 15) * SLOTU;
      u32 xv[4];
      #pragma unroll
      for (int j = 0; j < 4; ++j) {
        const int b = g * 16 + lhi * 4 + j;
        xv[j] = ld_sc1_u32(xsl + (size_t)b * 512 + n);
      }
      const int cur = t & 1;
      f32x4 acc = {0.f,0.f,0.f,0.f};
      if (t > 0) {
        stage3(h1r + (size_t)((t - 1) & 3) * SLOTU + goff, cur);
        __syncthreads();
        mm3(cur, acc);
        vm0_fence();                    // xv certainly landed (covered by stage3 too)
      } else {
        vm0_fence();
      }
      u32* wsl = h1r + (size_t)(t & 3) * SLOTU;
      u16 hbv[4], lbv[4];
      #pragma unroll
      for (int j = 0; j < 4; ++j) {
        const int b = g * 16 + lhi * 4 + j;
        const float h = fast_tanh(acc[j] + __builtin_bit_cast(float, xv[j]));
        hbv[j] = f2bf(h);
        lbv[j] = f2bf(h - bf2f(hbv[j]));
        st_sc1_u32(wsl + (size_t)b * 512 + n, (u32)hbv[j] | ((u32)lbv[j] << 16));
      }
      self_write(cur ^ 1, hbv, lbv);
      vm0_fence();                      // ring stores only (h1full not yet issued)
      __syncthreads();
      if (tid == 0) st_sc1_u32(&h1f[((g << 4) | (t & 15)) * 4 + cb], (u32)(t + 1));
      // h1full stores AFTER flag: never fenced in-loop; kernel-end drains
      #pragma unroll
      for (int j = 0; j < 4; ++j) {
        const int b = g * 16 + lhi * 4 + j;
        st_short_nt(h1full + ((size_t)b * S_ + t) * H_ + n, (u32)hbv[j]);
      }
    }
  }
}

// ---------------------------------------------------------------------------
// out = h1 @ Why^T + by. 64-row M-blocks (Why re-read /4 vs 16-row tiles).
// ---------------------------------------------------------------------------
__global__ void k_gemm_out(const u16* __restrict__ A, const float* __restrict__ Bw,
                           const float* __restrict__ bias, float* __restrict__ outp) {
  const int tid  = threadIdx.x;
  const int wave = tid >> 6, lane = tid & 63;
  const int l15 = lane & 15, lhi = lane >> 4;
  const int M0  = blockIdx.x * 64;
  const int ncb = wave * 64;

  #pragma unroll
  for (int nt = 0; nt < 4; ++nt) {
    const int nn = ncb + nt * 16 + l15;
    const float* wr = Bw + (size_t)nn * H_ + lhi * 8;
    bf16x8 w[16];
    #pragma unroll
    for (int ks = 0; ks < 16; ++ks) {
      const float* src = wr + ks * 32;
      bf16x8 ww;
      #pragma unroll
      for (int j = 0; j < 8; ++j) ww[j] = (short)f2bf(src[j]);
      w[ks] = ww;
    }
    const float bs = bias[nn];
    for (int mi = 0; mi < 4; ++mi) {
      const int m0 = M0 + mi * 16;
      const u16* arow = A + ((size_t)(m0 + l15)) * H_ + lhi * 8;
      f32x4 acc = {0.f, 0.f, 0.f, 0.f};
      #pragma unroll
      for (int ks = 0; ks < 16; ++ks) {
        bf16x8 a = *(const bf16x8*)(arow + ks * 32);
        acc = __builtin_amdgcn_mfma_f32_16x16x32_bf16(a, w[ks], acc, 0, 0, 0);
      }
      #pragma unroll
      for (int j = 0; j < 4; ++j)
        outp[(size_t)(m0 + lhi * 4 + j) * O_ + nn] = acc[j] + bs;
    }
  }
}

// ---------------------------------------------------------------------------
extern "C" void kernel_launch(void* const* d_in, const int* in_sizes, int n_in,
                              void* d_out, int out_size, void* d_ws, size_t ws_size,
                              hipStream_t stream) {
  const int*   ids = (const int*)d_in[0];
  const float* emb = (const float*)d_in[1];
  const float* Wxh = (const float*)d_in[2];
  const float* Whh = (const float*)d_in[3];
  const float* bh  = (const float*)d_in[4];
  const float* Why = (const float*)d_in[5];
  const float* by  = (const float*)d_in[6];
  float* out = (float*)d_out;

  char* ws = (char*)d_ws;
  size_t off = 0;
  float* EW0  = (float*)(ws + off); off += (size_t)V_ * H_ * 4;        // 256 KB
  u32* h0r    = (u32*)(ws + off);   off += (size_t)16 * SLOTU * 4;     // 2 MB
  u32* x1r    = (u32*)(ws + off);   off += (size_t)16 * SLOTU * 4;     // 2 MB
  u32* h1r    = (u32*)(ws + off);   off += (size_t)4 * SLOTU * 4;      // 512 KB
  u32* fa     = (u32*)(ws + off);   off += 4096;                       // flag arena
  u16* h1full = (u16*)(ws + off);   off += (size_t)B_ * S_ * H_ * 2;   // 67 MB

  // flag arena must be zero at the start of every call
  hipMemsetAsync(fa, 0, 4096, stream);

  k_embed<<<dim3(V_), dim3(256), 0, stream>>>(emb, Wxh, bh, EW0);

  k_pipe<<<dim3(48), dim3(512), 0, stream>>>(Whh, Wxh, ids, EW0, bh,
                                             h0r, x1r, h1r, h1full, fa);

  k_gemm_out<<<dim3((B_ * S_) / 64), dim3(256), 0, stream>>>(h1full, Why, by, out);
}